// Round 9
// baseline (191.344 us; speedup 1.0000x reference)
//
#include <hip/hip_runtime.h>
#include <hip/hip_bf16.h>
#include <math.h>

#define B_ 32
#define N_ 2048
#define C_ 64
#define M_ 512
#define KNN_ 32
#define RADIUS_ 0.4f
#define RCUT2 0.16016f        // conservative candidate cut (exact mask re-applied later)
#define GSCALE_ 6.2383246250f
#define TT 4                  // targets per block (amortizes Wb L2 stream)
#define NWAVE 16              // 1024 threads: 2 blocks/CU = 32 waves/CU (slot cap)
#define CANDCAP 128           // per-target candidate list cap (atomic slots)
#define NBLK 4096

typedef __attribute__((ext_vector_type(8))) short bf16x8;
typedef __attribute__((ext_vector_type(4))) float f32x4;
union FragU { uint4 q; bf16x8 h; unsigned int u[4]; };

// ---- main kernel LDS layout (dword offsets), TT=4, 1024 threads ----
// per-target region t*3208 (t<4), phase-overlaid:
//   phase A (P1/P3a):  Y[k][16] stride 17 at [0,544); FS hi [k2][64] s=66
//                      at [560,1616)   (bf16-RNE f only)
//   phase B (P3b/P4):  zh plane [p][j] bf16, row stride 200 hw, at hw [0,3200)
//                      zl plane at hw [3200,6400)   (16B-aligned rows)
// cand u64 [4t][128]: dwords [6416, 7440) -- overlays regions 2,3; dead after
//   select (barrier), before any Y/FS write there.  Slots via LDS atomicAdd.
// WGT transposed [t][s][k] f32: [12832, 13216), per-t stride 96
#define ZT_ 3208
#define ZTH (ZT_*2)            // 6416 halfwords per target region
#define RSTH 200               // z row stride (halfwords); 400B = 16B-aligned
#define ZLOFF 3200             // zl plane offset (halfwords) within region
#define FSH 560
#define CAND_OFF 6416
#define WGT_OFF  12832
#define WGT_TS   96
#define SM_TOTAL 13216         // 52864 B -> 2 blocks/CU, 32 waves/CU

// v_cvt_pk_bf16_f32: D.lo16 = bf16_rne(a), D.hi16 = bf16_rne(b) — one VALU op.
__device__ inline unsigned cvt_pk_bf16(float a, float b) {
    unsigned r;
    asm("v_cvt_pk_bf16_f32 %0, %1, %2" : "=v"(r) : "v"(a), "v"(b));
    return r;
}

// Pair split via cvt_pk: hw = hi(a0)|hi(a1)<<16, lw = lo(a0)|lo(a1)<<16.
// hi = RNE-bf16(a), lo = RNE-bf16(a - hi): residual bound 2^-18|a|.
__device__ inline void split_pair(float a0, float a1, unsigned& hw, unsigned& lw) {
    hw = cvt_pk_bf16(a0, a1);
    float r0 = a0 - __uint_as_float(hw << 16);
    float r1 = a1 - __uint_as_float(hw & 0xffff0000u);
    lw = cvt_pk_bf16(r0, r1);
}

// =====================================================================
// Setup kernel: W0..W3 -> single-bf16 (RNE) B-fragments for mfma 16x16x32.
// frag id = (l*6+ks)*4+nt.
// =====================================================================
__global__ __launch_bounds__(256) void wsplit_kernel(
    const float* __restrict__ W0, const float* __restrict__ W1,
    const float* __restrict__ W2, const float* __restrict__ W3,
    uint4* __restrict__ Wb)
{
    int gid = blockIdx.x * 256 + threadIdx.x;      // 96 frags * 64 lanes = 6144
    int lane = gid & 63, frag = gid >> 6;
    int nt = frag & 3;
    int ls = frag >> 2, ks = ls % 6, l = ls / 6;
    const float* W = (l==0) ? W0 : (l==1) ? W1 : (l==2) ? W2 : W3;
    int n = nt*16 + (lane & 15), quad = lane >> 4;
    unsigned int d[4];
    #pragma unroll
    for (int dd = 0; dd < 4; ++dd) {
        unsigned int two[2];
        #pragma unroll
        for (int e = 0; e < 2; ++e) {
            int k = ks*32 + quad*8 + dd*2 + e;
            __hip_bfloat16 hb = __float2bfloat16(W[k*64 + n]);   // RNE
            two[e] = *(unsigned short*)&hb;
        }
        d[dd] = two[0] | (two[1] << 16);
    }
    Wb[(size_t)frag*64 + lane] = make_uint4(d[0], d[1], d[2], d[3]);
}

// =====================================================================
// Main kernel (TT=4, 1024 thr, 2 blocks/CU = 32 waves/CU): fused KNN
// (register scan, LDS-atomic candidate compaction) + SH/weights + MFMA
// z-einsum (wave = (t, n-tile), barrier-split read/write phases, two-
// plane bf16 z) + MFMA slab matmul (wave = (band, n-tile), perm-free
// A-frags, pipelined disjoint Wb streams) + in-register band norms
// =====================================================================
__global__ __launch_bounds__(1024, 8) void main_kernel(
    const float* __restrict__ points, const float* __restrict__ feats,
    const float* __restrict__ b0, const uint4* __restrict__ Wb,
    unsigned int* __restrict__ hmax,
    const float* __restrict__ Wfc1, const float* __restrict__ Wfc2,
    float* __restrict__ dummy)
{
    __shared__ __align__(16) float smem[SM_TOTAL];
    __shared__ int sh_nbr[TT][32];
    __shared__ int sh_cnt[TT];
    __shared__ int cnt4[TT];
    unsigned int* smemU = (unsigned int*)smem;
    unsigned short* smemH = (unsigned short*)smem;
    const int tid = threadIdx.x;
    const int b = blockIdx.x >> 7;
    const int mbase = (blockIdx.x & 127) * TT;
    const float* pb = points + (size_t)b * N_ * 3;
    const int wv = tid >> 6, lane = tid & 63;

    // L3 warmup for the downstream FC chain (consumed at the end).
    float wm1 = Wfc1[(size_t)blockIdx.x*32 + (tid & 31)];   // 4096*32 = |Wfc1|
    float wm2 = Wfc2[(size_t)blockIdx.x*32 + (tid & 31)];   // 4096*32 = |Wfc2|

    // b0 preload for this wave's n-tile (band==0 only uses it)
    float b0r = b0[(wv >> 2)*16 + (lane & 15)];

    if (tid < TT) cnt4[tid] = 0;
    __syncthreads();

    // ---- KNN scan: register-resident. Wave scans its 1/16 (128 points,
    //      2 per lane) against all TT targets; hits claim a slot in the
    //      per-target list via LDS atomicAdd (hit rate ~1%/iter). ----
    {
        unsigned long long* cand = (unsigned long long*)&smem[CAND_OFF];
        float tx[TT], ty[TT], tz[TT];
        #pragma unroll
        for (int c = 0; c < TT; ++c) {
            int m4 = 4*(mbase + c);
            tx[c] = pb[3*m4]; ty[c] = pb[3*m4+1]; tz[c] = pb[3*m4+2];
        }
        const float* ps = pb + 3*(wv*128 + lane);
        #pragma unroll
        for (int it = 0; it < 2; ++it) {
            float px = ps[it*192+0], py = ps[it*192+1], pz = ps[it*192+2];
            int i = wv*128 + it*64 + lane;
            #pragma unroll
            for (int c = 0; c < TT; ++c) {
                float dx = px - tx[c], dy = py - ty[c], dz = pz - tz[c];
                float d2 = fmaf(dx,dx, fmaf(dy,dy, dz*dz));
                if (d2 <= RCUT2) {
                    int slot = atomicAdd(&cnt4[c], 1);
                    if (slot < CANDCAP)
                        cand[(c<<7) + slot] =
                            ((unsigned long long)__float_as_uint(d2) << 32) | (unsigned)i;
                }
            }
        }
    }
    __syncthreads();   // cand + cnt4 visible

    // ---- select: wave t (t<4) picks the 32-smallest SET from its list ----
    if (wv < TT) {
        unsigned long long* cand = (unsigned long long*)&smem[CAND_OFF];
        const int t = wv;
        int C = cnt4[t]; C = C < CANDCAP ? C : CANDCAP;
        unsigned long long kv0 = (lane < C)      ? cand[(t<<7) + lane]      : ~0ull;
        unsigned long long kv1 = (64 + lane < C) ? cand[(t<<7) + 64 + lane] : ~0ull;
        const unsigned long long lmask = (1ull << lane) - 1ull;
        if (C <= KNN_) {
            if (lane < KNN_) sh_nbr[t][lane] = (lane < C) ? (int)(kv0 & 0xffffffffu) : 0;
            if (lane == 0) sh_cnt[t] = C;
        } else {
            // Radix-select: largest thr with #{d2 < thr} < 32, on the d2
            // bit pattern (d2 in [0,0.25) => bits < 2^30, 30-step descent).
            unsigned d0 = (unsigned)(kv0 >> 32);   // invalid lanes = 0xFFFFFFFF
            unsigned d1 = (unsigned)(kv1 >> 32);
            unsigned thr = 0u;
            for (int bit = 29; bit >= 0; --bit) {
                unsigned mid = thr | (1u << bit);
                int cnt = __popcll(__ballot(d0 < mid)) + __popcll(__ballot(d1 < mid));
                if (cnt < KNN_) thr = mid;
            }
            // strictly-less set (size <= 31) + first E equals by lane order
            bool le0 = d0 < thr, le1 = d1 < thr;
            int cntL = __popcll(__ballot(le0)) + __popcll(__ballot(le1));
            int E = KNN_ - cntL;                   // >= 1; #equals >= E
            unsigned long long me0 = __ballot(d0 == thr);
            unsigned long long me1 = __ballot(d1 == thr);
            int e0 = __popcll(me0);
            bool sel0 = le0 || ((d0 == thr) && (__popcll(me0 & lmask) < E));
            bool sel1 = le1 || ((d1 == thr) && (e0 + __popcll(me1 & lmask) < E));
            unsigned long long ms0 = __ballot(sel0);
            if (sel0) sh_nbr[t][__popcll(ms0 & lmask)] = (int)(kv0 & 0xffffffffu);
            int base0 = __popcll(ms0);
            unsigned long long ms1 = __ballot(sel1);
            if (sel1) sh_nbr[t][base0 + __popcll(ms1 & lmask)] = (int)(kv1 & 0xffffffffu);
            if (lane == 0) sh_cnt[t] = KNN_;
        }
    }
    __syncthreads();   // sh_nbr visible; cand dead (regions 2,3 writable)

    // ---- P1: wave = (t = wv&3, kh = wv>>2). Feats gather pre-issued into
    //      registers; geometry on waves 0..3 lanes 0..31; FS staging 4 pairs
    //      (bf16-RNE hi only).
    {
        const int t = wv & 3, kh = wv >> 2;
        const float* fb = feats + (size_t)b * N_ * C_;
        float fv0[4], fv1[4];
        #pragma unroll
        for (int j = 0; j < 4; ++j) {
            int k2 = kh*4 + j;
            fv0[j] = fb[(size_t)sh_nbr[t][2*k2]   * C_ + lane];
            fv1[j] = fb[(size_t)sh_nbr[t][2*k2+1] * C_ + lane];
        }
        if (wv < TT && lane < 32) {
            int k = lane;
            int n = sh_nbr[t][k];
            int m4 = 4*(mbase + t);
            float x = pb[3*n]   - pb[3*m4];
            float y = pb[3*n+1] - pb[3*m4+1];
            float z = pb[3*n+2] - pb[3*m4+2];
            float d2 = x*x + y*y + z*z;
            float dist = sqrtf(fmaxf(d2, 1e-12f));
            float inv = 1.0f / dist;
            float dx = x*inv, dy = y*inv, dz = z*inv;
            float x2 = dx*dx, y2 = dy*dy, z2 = dz*dz;
            float yv[16];
            yv[0]  = 0.282095f;
            yv[1]  = 0.488603f*dy;  yv[2] = 0.488603f*dz;  yv[3] = 0.488603f*dx;
            yv[4]  = 1.092548f*dx*dy;
            yv[5]  = 1.092548f*dy*dz;
            yv[6]  = 0.315392f*(3.0f*z2-1.0f);
            yv[7]  = 1.092548f*dx*dz;
            yv[8]  = 0.546274f*(x2-y2);
            yv[9]  = 0.590044f*dy*(3.0f*x2-y2);
            yv[10] = 2.890611f*dx*dy*dz;
            yv[11] = 0.457046f*dy*(5.0f*z2-1.0f);
            yv[12] = 0.373176f*dz*(5.0f*z2-3.0f);
            yv[13] = 0.457046f*dx*(5.0f*z2-1.0f);
            yv[14] = 1.445306f*dz*(x2-y2);
            yv[15] = 0.590044f*dx*(x2-3.0f*y2);
            float* Yp = &smem[t*ZT_ + k*17];
            #pragma unroll
            for (int p = 0; p < 16; ++p) Yp[p] = yv[p];
            float dn = dist * (1.0f/RADIUS_);
            bool ok = (k < sh_cnt[t]) && (dn <= 1.0f);
            float w0 = 0.f, w1 = 0.f, w2 = 0.f;
            if (ok) {
                float dd0 = dn, dd1 = dn - 0.5f, dd2 = dn - 1.0f;
                w0 = __expf(-GSCALE_*dd0*dd0);
                w1 = __expf(-GSCALE_*dd1*dd1);
                w2 = __expf(-GSCALE_*dd2*dd2);
            }
            float s0 = w0, s1 = w1, s2 = w2;
            #pragma unroll
            for (int off = 16; off >= 1; off >>= 1) {
                s0 += __shfl_xor(s0, off);
                s1 += __shfl_xor(s1, off);
                s2 += __shfl_xor(s2, off);
            }
            w0 /= (s0 + 1e-8f);
            w1 /= (s1 + 1e-8f);
            w2 /= (s2 + 1e-8f);
            // transposed WGT[t][s][k]: conflict-free broadcast reads in P3
            smem[WGT_OFF + t*WGT_TS +      k] = w0;
            smem[WGT_OFF + t*WGT_TS + 32 + k] = w1;
            smem[WGT_OFF + t*WGT_TS + 64 + k] = w2;
        }
        // stage FS hi (loads issued above; latency hidden under geometry VALU)
        #pragma unroll
        for (int j = 0; j < 4; ++j) {
            int k2 = kh*4 + j;
            smemU[t*ZT_ + FSH + k2*66 + lane] = cvt_pk_bf16(fv0[j], fv1[j]);
        }
    }
    __syncthreads();   // Y, WGT, FS all visible

    // ---- P3a: z-einsum via MFMA. wave = (t, nh): ONE n-tile each.
    //      A = (Y.w_s) in hi/lo bf16 (2^-18 acc), B = bf16 f. ----
    f32x4 zacc[3];
    {
        const int t = wv & 3, nh = wv >> 2;
        const int quad = lane >> 4, col = lane & 15;
        float yv8[8];
        #pragma unroll
        for (int d = 0; d < 8; ++d)
            yv8[d] = smem[t*ZT_ + (quad*8 + d)*17 + col];
        FragU ah[3], al[3];
        #pragma unroll
        for (int s = 0; s < 3; ++s) {
            #pragma unroll
            for (int i = 0; i < 4; ++i) {
                float we = smem[WGT_OFF + t*WGT_TS + s*32 + quad*8 + 2*i];
                float wo = smem[WGT_OFF + t*WGT_TS + s*32 + quad*8 + 2*i + 1];
                split_pair(yv8[2*i]*we, yv8[2*i+1]*wo, ah[s].u[i], al[s].u[i]);
            }
        }
        #pragma unroll
        for (int s = 0; s < 3; ++s) zacc[s] = (f32x4){0.f,0.f,0.f,0.f};
        int n = nh*16 + col;
        FragU bh;
        #pragma unroll
        for (int i = 0; i < 4; ++i) {
            int k2 = quad*4 + i;
            bh.u[i] = smemU[t*ZT_ + FSH + k2*66 + n];
        }
        #pragma unroll
        for (int s = 0; s < 3; ++s) {
            zacc[s] = __builtin_amdgcn_mfma_f32_16x16x32_bf16(ah[s].h, bh.h, zacc[s], 0, 0, 0);
            zacc[s] = __builtin_amdgcn_mfma_f32_16x16x32_bf16(al[s].h, bh.h, zacc[s], 0, 0, 0);
        }
    }
    __syncthreads();   // ALL waves' Y/FS reads drained before z planes overwrite

    // ---- P3b: write zh/zl planes as bf16 halfwords (disjoint j per wave) ----
    {
        const int t = wv & 3, nh = wv >> 2;
        const int quad = lane >> 4, col = lane & 15;
        #pragma unroll
        for (int s = 0; s < 3; ++s) {
            #pragma unroll
            for (int r = 0; r < 4; ++r) {
                int p = quad*4 + r;
                int j = s*64 + nh*16 + col;
                float a = zacc[s][r];
                unsigned th = cvt_pk_bf16(a, a);            // lo16 = bf16(a)
                smemH[t*ZTH + p*RSTH + j] = (unsigned short)th;
                float res = a - __uint_as_float(th << 16);   // exact
                unsigned tl_ = cvt_pk_bf16(res, res);
                smemH[t*ZTH + ZLOFF + p*RSTH + j] = (unsigned short)tl_;
            }
        }
    }

    // ---- P4: slab matmul; wave = (band, nq): ONE n-tile each. Perm-free
    //      A-frags from zh/zl planes; disjoint 6KB Wb stream per wave,
    //      software-pipelined (ks=0 issued before the z barrier).
    {
        const int bp0[4] = {0,1,4,9};
        const int bsz[4] = {1,3,5,7};
        const int band = wv & 3, nq = wv >> 2;
        FragU bcur, bnxt;
        bcur.q = Wb[(size_t)((band*6 + 0)*4 + nq)*64 + lane];
        __syncthreads();   // z planes fully visible (Wb load already in flight)

        const int sz = bsz[band], p0 = bp0[band];
        const int rows = 2*sz;
        const int quad = lane >> 4, col = lane & 15;
        int gc = col < rows-1 ? col : rows-1;
        int tl = gc >= sz ? 1 : 0;
        int pA = p0 + gc - tl*sz;
        const unsigned hbA = tl*ZTH + pA*RSTH;     // halfword base, target {0,1}
        const unsigned hbB = hbA + 2*ZTH;          // target {2,3}, same p
        f32x4 acc[2];                              // [ti]
        acc[0] = (f32x4){0.f,0.f,0.f,0.f};
        acc[1] = (f32x4){0.f,0.f,0.f,0.f};

        #pragma unroll
        for (int ks = 0; ks < 6; ++ks) {
            if (ks < 5)
                bnxt.q = Wb[(size_t)((band*6 + ks+1)*4 + nq)*64 + lane];
            FragU ahA, alA, ahB, alB;
            ahA.q = *(const uint4*)&smemH[hbA + ks*32 + quad*8];
            alA.q = *(const uint4*)&smemH[hbA + ZLOFF + ks*32 + quad*8];
            ahB.q = *(const uint4*)&smemH[hbB + ks*32 + quad*8];
            alB.q = *(const uint4*)&smemH[hbB + ZLOFF + ks*32 + quad*8];
            acc[0] = __builtin_amdgcn_mfma_f32_16x16x32_bf16(ahA.h, bcur.h, acc[0], 0, 0, 0);
            acc[0] = __builtin_amdgcn_mfma_f32_16x16x32_bf16(alA.h, bcur.h, acc[0], 0, 0, 0);
            acc[1] = __builtin_amdgcn_mfma_f32_16x16x32_bf16(ahB.h, bcur.h, acc[1], 0, 0, 0);
            acc[1] = __builtin_amdgcn_mfma_f32_16x16x32_bf16(alB.h, bcur.h, acc[1], 0, 0, 0);
            bcur = bnxt;
        }
        // In-register band norms for 4 targets; quad-reduce via shfl_xor(16/32).
        float sq[4];                               // [tg = ti*2 + tl2]
        #pragma unroll
        for (int tg = 0; tg < 4; ++tg) sq[tg] = 0.f;
        #pragma unroll
        for (int r = 0; r < 4; ++r) {
            int row = quad*4 + r;
            bool valid = row < rows;
            int tl2 = row >= sz ? 1 : 0;
            #pragma unroll
            for (int ti = 0; ti < 2; ++ti) {
                float o = acc[ti][r];
                if (band == 0) o += b0r;
                if (valid) sq[ti*2 + tl2] += o*o;
            }
        }
        #pragma unroll
        for (int tg = 0; tg < 4; ++tg) {
            float v = sq[tg];
            v += __shfl_xor(v, 16);
            v += __shfl_xor(v, 32);
            sq[tg] = v;
        }
        if (quad == 0) {
            float m = fmaxf(fmaxf(sq[0], sq[1]), fmaxf(sq[2], sq[3]));
            float h = sqrtf(fmaxf(m, 1e-8f));
            // biased key: order-preserving, beats the 0xAA poison -> no memset.
            atomicMax(&hmax[b*256 + band*64 + nq*16 + col],
                      __float_as_uint(h) ^ 0x80000000u);
        }
    }

    // consume the warmup loads (branch practically never taken)
    if (__float_as_uint(wm1 + wm2) == 0xdeadbeefu) dummy[0] = wm1;
}

// =====================================================================
// FC head, round-8 split (evidence: 5-dispatch split beat merged fc23).
// =====================================================================
__global__ __launch_bounds__(256) void fc1_kernel(
    const unsigned int* __restrict__ hmaxk,
    const float* __restrict__ Wfc1, const float* __restrict__ bfc1,
    float* __restrict__ t1)
{
    __shared__ float h[256];
    __shared__ float red[4][80];
    const int b = blockIdx.x >> 3, uc = blockIdx.x & 7;
    const int tid = threadIdx.x;
    const int u = tid & 63, iq = tid >> 6;
    h[tid] = __uint_as_float(hmaxk[b*256 + tid] ^ 0x80000000u);
    __syncthreads();
    float acc = 0.f;
    const float* Wp = Wfc1 + uc*64 + u;
    #pragma unroll 8
    for (int i = iq*64; i < iq*64 + 64; ++i)
        acc = fmaf(h[i], Wp[(size_t)i*512], acc);
    red[iq][u] = acc;
    __syncthreads();
    if (iq == 0) {
        float s = red[0][u] + red[1][u] + red[2][u] + red[3][u] + bfc1[uc*64 + u];
        t1[b*512 + uc*64 + u] = fmaxf(s, 0.f);
    }
}

__global__ __launch_bounds__(256) void fc2_kernel(
    const float* __restrict__ t1,
    const float* __restrict__ Wfc2, const float* __restrict__ bfc2,
    float* __restrict__ t2)
{
    __shared__ float t1s[512];
    __shared__ float red[4][80];
    const int b = blockIdx.x >> 2, uc = blockIdx.x & 3;
    const int tid = threadIdx.x;
    const int u = tid & 63, isl = tid >> 6;
    t1s[tid]       = t1[b*512 + tid];
    t1s[256 + tid] = t1[b*512 + 256 + tid];
    __syncthreads();
    float acc = 0.f;
    const float* Wp = Wfc2 + uc*64 + u;
    #pragma unroll 8
    for (int i = isl*128; i < isl*128 + 128; ++i)
        acc = fmaf(t1s[i], Wp[(size_t)i*256], acc);
    red[isl][u] = acc;
    __syncthreads();
    if (isl == 0) {
        float s = red[0][u] + red[1][u] + red[2][u] + red[3][u] + bfc2[uc*64 + u];
        t2[b*256 + uc*64 + u] = fmaxf(s, 0.f);
    }
}

__global__ __launch_bounds__(256) void fc3_kernel(
    const float* __restrict__ t2,
    const float* __restrict__ Wsm, const float* __restrict__ bsm,
    float* __restrict__ out)
{
    __shared__ float t2s[256];
    __shared__ float red[4][80];
    const int b = blockIdx.x;
    const int tid = threadIdx.x;
    const int u = tid & 63, isl = tid >> 6;
    t2s[tid] = t2[b*256 + tid];
    __syncthreads();
    float acc = 0.f;
    if (u < 40) {
        #pragma unroll 8
        for (int i = isl*64; i < isl*64 + 64; ++i)
            acc = fmaf(t2s[i], Wsm[(size_t)i*40 + u], acc);
    }
    red[isl][u] = acc;
    __syncthreads();
    if (tid < 64) {
        float s = red[0][tid] + red[1][tid] + red[2][tid] + red[3][tid];
        float x = (tid < 40) ? (s + bsm[tid]) : -1e30f;
        float mx = x;
        #pragma unroll
        for (int off = 32; off >= 1; off >>= 1) mx = fmaxf(mx, __shfl_xor(mx, off));
        float e = (tid < 40) ? expf(x - mx) : 0.f;
        float ssum = e;
        #pragma unroll
        for (int off = 32; off >= 1; off >>= 1) ssum += __shfl_xor(ssum, off);
        if (tid < 40) out[b*40 + tid] = e / ssum;
    }
}

extern "C" void kernel_launch(void* const* d_in, const int* in_sizes, int n_in,
                              void* d_out, int out_size, void* d_ws, size_t ws_size,
                              hipStream_t stream)
{
    const float* points = (const float*)d_in[0];
    const float* feats  = (const float*)d_in[1];
    const float* W0   = (const float*)d_in[2];
    const float* b0   = (const float*)d_in[3];
    const float* W1   = (const float*)d_in[4];
    const float* W2   = (const float*)d_in[5];
    const float* W3   = (const float*)d_in[6];
    const float* Wfc1 = (const float*)d_in[7];
    const float* bfc1 = (const float*)d_in[8];
    const float* Wfc2 = (const float*)d_in[9];
    const float* bfc2 = (const float*)d_in[10];
    const float* Wsm  = (const float*)d_in[11];
    const float* bsm  = (const float*)d_in[12];
    float* out = (float*)d_out;

    char* ws = (char*)d_ws;
    unsigned int* hmax = (unsigned int*)ws;              // 32 KB (poison OK, biased keys)
    float* t1 = (float*)(ws + 32*1024);                  // 64 KB
    float* t2 = (float*)(ws + 96*1024);                  // 32 KB
    float* dummy = (float*)(ws + 120*1024);              // warmup sink
    uint4* Wb = (uint4*)(ws + 128*1024);                 // 96 KB (single-bf16 W)

    wsplit_kernel<<<24, 256, 0, stream>>>(W0, W1, W2, W3, Wb);
    main_kernel<<<NBLK, 1024, 0, stream>>>(points, feats, b0, Wb, hmax,
                                           Wfc1, Wfc2, dummy);
    fc1_kernel<<<256, 256, 0, stream>>>(hmax, Wfc1, bfc1, t1);
    fc2_kernel<<<128, 256, 0, stream>>>(t1, Wfc2, bfc2, t2);
    fc3_kernel<<<32, 256, 0, stream>>>(t2, Wsm, bsm, out);
}

// Round 10
// 154.990 us; speedup vs baseline: 1.2346x; 1.2346x over previous
//
#include <hip/hip_runtime.h>
#include <hip/hip_bf16.h>
#include <math.h>

#define B_ 32
#define N_ 2048
#define C_ 64
#define M_ 512
#define KNN_ 32
#define RADIUS_ 0.4f
#define RCUT2 0.16016f        // conservative candidate cut (exact mask re-applied later)
#define GSCALE_ 6.2383246250f
#define TT 4                  // targets per block (amortizes Wb L2 stream)
#define NWAVE 8               // 512 threads; ~28KB LDS -> 4 blocks/CU = 32 waves/CU
#define SEGCAP 40             // per-(wave,target) candidate segment cap
#define NBLK 4096

typedef __attribute__((ext_vector_type(8))) short bf16x8;
typedef __attribute__((ext_vector_type(4))) float f32x4;
union FragU { uint4 q; bf16x8 h; unsigned int u[4]; };

// ---- main kernel LDS layout (dword offsets), TT=4, 512 threads ----
// per-target region t*1616 (t<4), phase-overlaid:
//   phase A (P1/P3a):  Y[k][16] stride 17 at [0,544); FS hi [k2][64] s=66
//                      at [560,1616)   (bf16-RNE f only)
//   phase B (P3b/P4):  zh plane [p][j] bf16, row stride 200 hw, hw [0,3200)
//                      (z bf16-RNE only — z-lo dropped, see accuracy budget)
// cand u64 [8w][4t][SEGCAP]: dwords [3232, 5792) -- overlays regions 2,3;
//   dead after select (barrier), before any Y/FS write there.
// WGT transposed [t][s][k] f32: [6464, 6848), per-t stride 96
#define ZT_ 1616
#define ZTH (ZT_*2)            // 3232 halfwords per target region
#define RSTH 200               // z row stride (halfwords); 400B = 16B-aligned
#define FSH 560
#define CAND_OFF 3232
#define WGT_OFF  6464
#define WGT_TS   96
#define SM_TOTAL 6848          // 27392 B (+~1.3KB arrays) -> 4 blocks/CU (wave cap)

// v_cvt_pk_bf16_f32: D.lo16 = bf16_rne(a), D.hi16 = bf16_rne(b) — one VALU op.
__device__ inline unsigned cvt_pk_bf16(float a, float b) {
    unsigned r;
    asm("v_cvt_pk_bf16_f32 %0, %1, %2" : "=v"(r) : "v"(a), "v"(b));
    return r;
}

// Pair split via cvt_pk: hw = hi(a0)|hi(a1)<<16, lw = lo(a0)|lo(a1)<<16.
// hi = RNE-bf16(a), lo = RNE-bf16(a - hi): residual bound 2^-18|a|.
__device__ inline void split_pair(float a0, float a1, unsigned& hw, unsigned& lw) {
    hw = cvt_pk_bf16(a0, a1);
    float r0 = a0 - __uint_as_float(hw << 16);
    float r1 = a1 - __uint_as_float(hw & 0xffff0000u);
    lw = cvt_pk_bf16(r0, r1);
}

// =====================================================================
// Setup kernel: W0..W3 -> single-bf16 (RNE) B-fragments for mfma 16x16x32.
// frag id = (l*6+ks)*4+nt.
// =====================================================================
__global__ __launch_bounds__(256) void wsplit_kernel(
    const float* __restrict__ W0, const float* __restrict__ W1,
    const float* __restrict__ W2, const float* __restrict__ W3,
    uint4* __restrict__ Wb)
{
    int gid = blockIdx.x * 256 + threadIdx.x;      // 96 frags * 64 lanes = 6144
    int lane = gid & 63, frag = gid >> 6;
    int nt = frag & 3;
    int ls = frag >> 2, ks = ls % 6, l = ls / 6;
    const float* W = (l==0) ? W0 : (l==1) ? W1 : (l==2) ? W2 : W3;
    int n = nt*16 + (lane & 15), quad = lane >> 4;
    unsigned int d[4];
    #pragma unroll
    for (int dd = 0; dd < 4; ++dd) {
        unsigned int two[2];
        #pragma unroll
        for (int e = 0; e < 2; ++e) {
            int k = ks*32 + quad*8 + dd*2 + e;
            __hip_bfloat16 hb = __float2bfloat16(W[k*64 + n]);   // RNE
            two[e] = *(unsigned short*)&hb;
        }
        d[dd] = two[0] | (two[1] << 16);
    }
    Wb[(size_t)frag*64 + lane] = make_uint4(d[0], d[1], d[2], d[3]);
}

// =====================================================================
// Main kernel (TT=4, 512 thr, 4 blocks/CU = 32 waves/CU): fused KNN
// (register scan) + SH/weights + MFMA z-einsum (wave = (t, n-half),
// barrier-split read/write phases, single-plane bf16 z) + MFMA slab
// matmul (wave = (band, n-half), perm-free A-frags, pipelined disjoint
// Wb streams) + in-register band norms + atomicMax
// =====================================================================
__global__ __launch_bounds__(512, 8) void main_kernel(
    const float* __restrict__ points, const float* __restrict__ feats,
    const float* __restrict__ b0, const uint4* __restrict__ Wb,
    unsigned int* __restrict__ hmax,
    const float* __restrict__ Wfc1, const float* __restrict__ Wfc2,
    float* __restrict__ dummy)
{
    __shared__ __align__(16) float smem[SM_TOTAL];
    __shared__ int sh_nbr[TT][32];
    __shared__ int sh_cnt[TT];
    __shared__ int cntk[NWAVE*TT];
    unsigned int* smemU = (unsigned int*)smem;
    unsigned short* smemH = (unsigned short*)smem;
    const int tid = threadIdx.x;
    const int b = blockIdx.x >> 7;
    const int mbase = (blockIdx.x & 127) * TT;
    const float* pb = points + (size_t)b * N_ * 3;
    const int wv = tid >> 6, lane = tid & 63;

    // L3 warmup for the downstream FC chain (consumed at the end).
    float wm1 = Wfc1[(size_t)blockIdx.x*32 + (tid & 31)];   // 4096*32 = |Wfc1|
    float wm2 = Wfc2[(size_t)blockIdx.x*32 + (tid & 31)];   // 4096*32 = |Wfc2|

    // b0 preload for this wave's two n-tiles (band==0 only uses it)
    const int nh_pre = wv >> 2;
    float b0r[2];
    #pragma unroll
    for (int ntl = 0; ntl < 2; ++ntl)
        b0r[ntl] = b0[(nh_pre*2 + ntl)*16 + (lane & 15)];

    // ---- KNN scan: register-resident. Wave scans its eighth (256 points,
    //      4 per lane) against all TT targets. ----
    {
        unsigned long long* cand = (unsigned long long*)&smem[CAND_OFF];
        float tx[TT], ty[TT], tz[TT];
        #pragma unroll
        for (int c = 0; c < TT; ++c) {
            int m4 = 4*(mbase + c);
            tx[c] = pb[3*m4]; ty[c] = pb[3*m4+1]; tz[c] = pb[3*m4+2];
        }
        float px[4], py[4], pz[4];
        const float* ps = pb + 3*(wv*256 + lane);
        #pragma unroll
        for (int it = 0; it < 4; ++it) {
            px[it] = ps[it*192+0]; py[it] = ps[it*192+1]; pz[it] = ps[it*192+2];
        }
        int bcnt[TT];
        #pragma unroll
        for (int c = 0; c < TT; ++c) bcnt[c] = 0;
        #pragma unroll
        for (int it = 0; it < 4; ++it) {
            int i = wv*256 + it*64 + lane;
            #pragma unroll
            for (int c = 0; c < TT; ++c) {
                float dx = px[it] - tx[c], dy = py[it] - ty[c], dz = pz[it] - tz[c];
                float d2 = fmaf(dx,dx, fmaf(dy,dy, dz*dz));
                bool isc = d2 <= RCUT2;
                unsigned long long mk = __ballot(isc);
                if (isc) {
                    int pos = bcnt[c] + __popcll(mk & ((1ull<<lane)-1ull));
                    if (pos < SEGCAP)
                        cand[(size_t)(wv*TT+c)*SEGCAP + pos] =
                            ((unsigned long long)__float_as_uint(d2) << 32) | (unsigned)i;
                }
                bcnt[c] += __popcll(mk);
            }
        }
        if (lane == 0) {
            #pragma unroll
            for (int c = 0; c < TT; ++c)
                cntk[wv*TT+c] = bcnt[c] < SEGCAP ? bcnt[c] : SEGCAP;
        }
    }
    __syncthreads();   // cand + cntk visible

    // ---- select: wave t (t<4) merges 8 segments, picks 32-smallest SET ----
    if (wv < TT) {
        unsigned long long* cand = (unsigned long long*)&smem[CAND_OFF];
        const int t = wv;
        int os[NWAVE+1];
        os[0] = 0;
        #pragma unroll
        for (int w = 0; w < NWAVE; ++w) os[w+1] = os[w] + cntk[w*TT+t];
        int C = os[NWAVE] < 128 ? os[NWAVE] : 128;
        auto fetch = [&](int pos) -> unsigned long long {
            if (pos >= C) return ~0ull;
            int ws = 0, base = 0;
            #pragma unroll
            for (int w = 1; w < NWAVE; ++w)
                if (pos >= os[w]) { ws = w; base = os[w]; }
            return cand[(size_t)(ws*TT+t)*SEGCAP + (pos - base)];
        };
        unsigned long long kv0 = fetch(lane), kv1 = fetch(64 + lane);
        const unsigned long long lmask = (1ull << lane) - 1ull;
        if (C <= KNN_) {
            if (lane < KNN_) sh_nbr[t][lane] = (lane < C) ? (int)(kv0 & 0xffffffffu) : 0;
            if (lane == 0) sh_cnt[t] = C;
        } else {
            // Radix-select: largest thr with #{d2 < thr} < 32, on the d2
            // bit pattern (d2 in [0,0.25) => bits < 2^30, 30-step descent).
            unsigned d0 = (unsigned)(kv0 >> 32);   // invalid lanes = 0xFFFFFFFF
            unsigned d1 = (unsigned)(kv1 >> 32);
            unsigned thr = 0u;
            for (int bit = 29; bit >= 0; --bit) {
                unsigned mid = thr | (1u << bit);
                int cnt = __popcll(__ballot(d0 < mid)) + __popcll(__ballot(d1 < mid));
                if (cnt < KNN_) thr = mid;
            }
            // strictly-less set (size <= 31) + first E equals by lane order
            bool le0 = d0 < thr, le1 = d1 < thr;
            int cntL = __popcll(__ballot(le0)) + __popcll(__ballot(le1));
            int E = KNN_ - cntL;                   // >= 1; #equals >= E
            unsigned long long me0 = __ballot(d0 == thr);
            unsigned long long me1 = __ballot(d1 == thr);
            int e0 = __popcll(me0);
            bool sel0 = le0 || ((d0 == thr) && (__popcll(me0 & lmask) < E));
            bool sel1 = le1 || ((d1 == thr) && (e0 + __popcll(me1 & lmask) < E));
            unsigned long long ms0 = __ballot(sel0);
            if (sel0) sh_nbr[t][__popcll(ms0 & lmask)] = (int)(kv0 & 0xffffffffu);
            int base0 = __popcll(ms0);
            unsigned long long ms1 = __ballot(sel1);
            if (sel1) sh_nbr[t][base0 + __popcll(ms1 & lmask)] = (int)(kv1 & 0xffffffffu);
            if (lane == 0) sh_cnt[t] = KNN_;
        }
    }
    __syncthreads();   // sh_nbr visible; cand dead (regions 2,3 writable)

    // ---- P1: wave = (t = wv&3, kh = wv>>2). Feats gather pre-issued into
    //      registers; geometry on waves 0..3 lanes 0..31; FS staging 8 pairs
    //      (bf16-RNE hi only).
    {
        const int t = wv & 3, kh = wv >> 2;
        const float* fb = feats + (size_t)b * N_ * C_;
        float fv0[8], fv1[8];
        #pragma unroll
        for (int j = 0; j < 8; ++j) {
            int k2 = kh*8 + j;
            fv0[j] = fb[(size_t)sh_nbr[t][2*k2]   * C_ + lane];
            fv1[j] = fb[(size_t)sh_nbr[t][2*k2+1] * C_ + lane];
        }
        if (wv < TT && lane < 32) {
            int k = lane;
            int n = sh_nbr[t][k];
            int m4 = 4*(mbase + t);
            float x = pb[3*n]   - pb[3*m4];
            float y = pb[3*n+1] - pb[3*m4+1];
            float z = pb[3*n+2] - pb[3*m4+2];
            float d2 = x*x + y*y + z*z;
            float dist = sqrtf(fmaxf(d2, 1e-12f));
            float inv = 1.0f / dist;
            float dx = x*inv, dy = y*inv, dz = z*inv;
            float x2 = dx*dx, y2 = dy*dy, z2 = dz*dz;
            float yv[16];
            yv[0]  = 0.282095f;
            yv[1]  = 0.488603f*dy;  yv[2] = 0.488603f*dz;  yv[3] = 0.488603f*dx;
            yv[4]  = 1.092548f*dx*dy;
            yv[5]  = 1.092548f*dy*dz;
            yv[6]  = 0.315392f*(3.0f*z2-1.0f);
            yv[7]  = 1.092548f*dx*dz;
            yv[8]  = 0.546274f*(x2-y2);
            yv[9]  = 0.590044f*dy*(3.0f*x2-y2);
            yv[10] = 2.890611f*dx*dy*dz;
            yv[11] = 0.457046f*dy*(5.0f*z2-1.0f);
            yv[12] = 0.373176f*dz*(5.0f*z2-3.0f);
            yv[13] = 0.457046f*dx*(5.0f*z2-1.0f);
            yv[14] = 1.445306f*dz*(x2-y2);
            yv[15] = 0.590044f*dx*(x2-3.0f*y2);
            float* Yp = &smem[t*ZT_ + k*17];
            #pragma unroll
            for (int p = 0; p < 16; ++p) Yp[p] = yv[p];
            float dn = dist * (1.0f/RADIUS_);
            bool ok = (k < sh_cnt[t]) && (dn <= 1.0f);
            float w0 = 0.f, w1 = 0.f, w2 = 0.f;
            if (ok) {
                float dd0 = dn, dd1 = dn - 0.5f, dd2 = dn - 1.0f;
                w0 = __expf(-GSCALE_*dd0*dd0);
                w1 = __expf(-GSCALE_*dd1*dd1);
                w2 = __expf(-GSCALE_*dd2*dd2);
            }
            float s0 = w0, s1 = w1, s2 = w2;
            #pragma unroll
            for (int off = 16; off >= 1; off >>= 1) {
                s0 += __shfl_xor(s0, off);
                s1 += __shfl_xor(s1, off);
                s2 += __shfl_xor(s2, off);
            }
            w0 /= (s0 + 1e-8f);
            w1 /= (s1 + 1e-8f);
            w2 /= (s2 + 1e-8f);
            // transposed WGT[t][s][k]: conflict-free broadcast reads in P3
            smem[WGT_OFF + t*WGT_TS +      k] = w0;
            smem[WGT_OFF + t*WGT_TS + 32 + k] = w1;
            smem[WGT_OFF + t*WGT_TS + 64 + k] = w2;
        }
        // stage FS hi (loads issued above; latency hidden under geometry VALU)
        #pragma unroll
        for (int j = 0; j < 8; ++j) {
            int k2 = kh*8 + j;
            smemU[t*ZT_ + FSH + k2*66 + lane] = cvt_pk_bf16(fv0[j], fv1[j]);
        }
    }
    __syncthreads();   // Y, WGT, FS all visible

    // ---- P3a: z-einsum via MFMA. wave = (t, nh): 2 n-tiles each.
    //      A = (Y.w_s) in hi/lo bf16 (2^-18 acc), B = bf16 f. ----
    f32x4 zacc[3][2];
    {
        const int t = wv & 3, nh = wv >> 2;
        const int quad = lane >> 4, col = lane & 15;
        float yv8[8];
        #pragma unroll
        for (int d = 0; d < 8; ++d)
            yv8[d] = smem[t*ZT_ + (quad*8 + d)*17 + col];
        FragU ah[3], al[3];
        #pragma unroll
        for (int s = 0; s < 3; ++s) {
            #pragma unroll
            for (int i = 0; i < 4; ++i) {
                float we = smem[WGT_OFF + t*WGT_TS + s*32 + quad*8 + 2*i];
                float wo = smem[WGT_OFF + t*WGT_TS + s*32 + quad*8 + 2*i + 1];
                split_pair(yv8[2*i]*we, yv8[2*i+1]*wo, ah[s].u[i], al[s].u[i]);
            }
        }
        #pragma unroll
        for (int s = 0; s < 3; ++s)
            #pragma unroll
            for (int nl = 0; nl < 2; ++nl) zacc[s][nl] = (f32x4){0.f,0.f,0.f,0.f};
        #pragma unroll
        for (int nl = 0; nl < 2; ++nl) {
            int n = (nh*2 + nl)*16 + col;
            FragU bh;
            #pragma unroll
            for (int i = 0; i < 4; ++i) {
                int k2 = quad*4 + i;
                bh.u[i] = smemU[t*ZT_ + FSH + k2*66 + n];
            }
            #pragma unroll
            for (int s = 0; s < 3; ++s) {
                zacc[s][nl] = __builtin_amdgcn_mfma_f32_16x16x32_bf16(ah[s].h, bh.h, zacc[s][nl], 0, 0, 0);
                zacc[s][nl] = __builtin_amdgcn_mfma_f32_16x16x32_bf16(al[s].h, bh.h, zacc[s][nl], 0, 0, 0);
            }
        }
    }
    __syncthreads();   // ALL waves' Y/FS reads drained before z plane overwrites

    // ---- P3b: write zh plane as bf16-RNE halfwords (disjoint j per wave) ----
    {
        const int t = wv & 3, nh = wv >> 2;
        const int quad = lane >> 4, col = lane & 15;
        #pragma unroll
        for (int s = 0; s < 3; ++s) {
            #pragma unroll
            for (int nl = 0; nl < 2; ++nl) {
                #pragma unroll
                for (int r = 0; r < 4; ++r) {
                    int p = quad*4 + r;
                    int j = s*64 + (nh*2+nl)*16 + col;
                    float a = zacc[s][nl][r];
                    smemH[t*ZTH + p*RSTH + j] =
                        (unsigned short)cvt_pk_bf16(a, a);
                }
            }
        }
    }

    // ---- P4: slab matmul; wave = (band, nh). Perm-free A-frags straight
    //      from the zh plane; single-bf16 W, software-pipelined Wb loads
    //      (ks=0 issued before the z barrier). In-register band norms.
    {
        const int bp0[4] = {0,1,4,9};
        const int bsz[4] = {1,3,5,7};
        const int band = wv & 3, nh = wv >> 2;
        FragU bcur[2], bnxt[2];
        #pragma unroll
        for (int ntl = 0; ntl < 2; ++ntl)
            bcur[ntl].q = Wb[(size_t)((band*6 + 0)*4 + nh*2 + ntl)*64 + lane];
        __syncthreads();   // z plane fully visible (Wb loads already in flight)

        const int sz = bsz[band], p0 = bp0[band];
        const int rows = 2*sz;
        const int quad = lane >> 4, col = lane & 15;
        int gc = col < rows-1 ? col : rows-1;
        int tl = gc >= sz ? 1 : 0;
        int pA = p0 + gc - tl*sz;
        const unsigned hbA = tl*ZTH + pA*RSTH;     // halfword base, target {0,1}
        const unsigned hbB = hbA + 2*ZTH;          // target {2,3}, same p
        f32x4 acc[2][2];                           // [ti][ntl]
        #pragma unroll
        for (int ti = 0; ti < 2; ++ti)
            #pragma unroll
            for (int ntl = 0; ntl < 2; ++ntl) acc[ti][ntl] = (f32x4){0.f,0.f,0.f,0.f};

        #pragma unroll
        for (int ks = 0; ks < 6; ++ks) {
            if (ks < 5) {
                #pragma unroll
                for (int ntl = 0; ntl < 2; ++ntl)
                    bnxt[ntl].q = Wb[(size_t)((band*6 + ks+1)*4 + nh*2 + ntl)*64 + lane];
            }
            FragU ahA, ahB;
            ahA.q = *(const uint4*)&smemH[hbA + ks*32 + quad*8];
            ahB.q = *(const uint4*)&smemH[hbB + ks*32 + quad*8];
            #pragma unroll
            for (int ntl = 0; ntl < 2; ++ntl) {
                acc[0][ntl] = __builtin_amdgcn_mfma_f32_16x16x32_bf16(ahA.h, bcur[ntl].h, acc[0][ntl], 0, 0, 0);
                acc[1][ntl] = __builtin_amdgcn_mfma_f32_16x16x32_bf16(ahB.h, bcur[ntl].h, acc[1][ntl], 0, 0, 0);
            }
            #pragma unroll
            for (int ntl = 0; ntl < 2; ++ntl) bcur[ntl] = bnxt[ntl];
        }
        // In-register band norms for 4 targets; quad-reduce via shfl_xor(16/32).
        float sq[2][4];                            // [ntl][tg = ti*2 + tl2]
        #pragma unroll
        for (int ntl = 0; ntl < 2; ++ntl)
            #pragma unroll
            for (int tg = 0; tg < 4; ++tg) sq[ntl][tg] = 0.f;
        #pragma unroll
        for (int r = 0; r < 4; ++r) {
            int row = quad*4 + r;
            bool valid = row < rows;
            int tl2 = row >= sz ? 1 : 0;
            #pragma unroll
            for (int ti = 0; ti < 2; ++ti) {
                #pragma unroll
                for (int ntl = 0; ntl < 2; ++ntl) {
                    float o = acc[ti][ntl][r];
                    if (band == 0) o += b0r[ntl];
                    if (valid) sq[ntl][ti*2 + tl2] += o*o;
                }
            }
        }
        #pragma unroll
        for (int ntl = 0; ntl < 2; ++ntl) {
            #pragma unroll
            for (int tg = 0; tg < 4; ++tg) {
                float v = sq[ntl][tg];
                v += __shfl_xor(v, 16);
                v += __shfl_xor(v, 32);
                sq[ntl][tg] = v;
            }
        }
        if (quad == 0) {
            #pragma unroll
            for (int ntl = 0; ntl < 2; ++ntl) {
                float m = fmaxf(fmaxf(sq[ntl][0], sq[ntl][1]),
                                fmaxf(sq[ntl][2], sq[ntl][3]));
                float h = sqrtf(fmaxf(m, 1e-8f));
                // biased key: order-preserving, beats the 0xAA poison -> no memset.
                atomicMax(&hmax[b*256 + band*64 + (nh*2 + ntl)*16 + col],
                          __float_as_uint(h) ^ 0x80000000u);
            }
        }
    }

    // consume the warmup loads (branch practically never taken)
    if (__float_as_uint(wm1 + wm2) == 0xdeadbeefu) dummy[0] = wm1;
}

// =====================================================================
// FC head, round-8 split (evidence: 5-dispatch split beat merged fc23).
// =====================================================================
__global__ __launch_bounds__(256) void fc1_kernel(
    const unsigned int* __restrict__ hmaxk,
    const float* __restrict__ Wfc1, const float* __restrict__ bfc1,
    float* __restrict__ t1)
{
    __shared__ float h[256];
    __shared__ float red[4][80];
    const int b = blockIdx.x >> 3, uc = blockIdx.x & 7;
    const int tid = threadIdx.x;
    const int u = tid & 63, iq = tid >> 6;
    h[tid] = __uint_as_float(hmaxk[b*256 + tid] ^ 0x80000000u);
    __syncthreads();
    float acc = 0.f;
    const float* Wp = Wfc1 + uc*64 + u;
    #pragma unroll 8
    for (int i = iq*64; i < iq*64 + 64; ++i)
        acc = fmaf(h[i], Wp[(size_t)i*512], acc);
    red[iq][u] = acc;
    __syncthreads();
    if (iq == 0) {
        float s = red[0][u] + red[1][u] + red[2][u] + red[3][u] + bfc1[uc*64 + u];
        t1[b*512 + uc*64 + u] = fmaxf(s, 0.f);
    }
}

__global__ __launch_bounds__(256) void fc2_kernel(
    const float* __restrict__ t1,
    const float* __restrict__ Wfc2, const float* __restrict__ bfc2,
    float* __restrict__ t2)
{
    __shared__ float t1s[512];
    __shared__ float red[4][80];
    const int b = blockIdx.x >> 2, uc = blockIdx.x & 3;
    const int tid = threadIdx.x;
    const int u = tid & 63, isl = tid >> 6;
    t1s[tid]       = t1[b*512 + tid];
    t1s[256 + tid] = t1[b*512 + 256 + tid];
    __syncthreads();
    float acc = 0.f;
    const float* Wp = Wfc2 + uc*64 + u;
    #pragma unroll 8
    for (int i = isl*128; i < isl*128 + 128; ++i)
        acc = fmaf(t1s[i], Wp[(size_t)i*256], acc);
    red[isl][u] = acc;
    __syncthreads();
    if (isl == 0) {
        float s = red[0][u] + red[1][u] + red[2][u] + red[3][u] + bfc2[uc*64 + u];
        t2[b*256 + uc*64 + u] = fmaxf(s, 0.f);
    }
}

__global__ __launch_bounds__(256) void fc3_kernel(
    const float* __restrict__ t2,
    const float* __restrict__ Wsm, const float* __restrict__ bsm,
    float* __restrict__ out)
{
    __shared__ float t2s[256];
    __shared__ float red[4][80];
    const int b = blockIdx.x;
    const int tid = threadIdx.x;
    const int u = tid & 63, isl = tid >> 6;
    t2s[tid] = t2[b*256 + tid];
    __syncthreads();
    float acc = 0.f;
    if (u < 40) {
        #pragma unroll 8
        for (int i = isl*64; i < isl*64 + 64; ++i)
            acc = fmaf(t2s[i], Wsm[(size_t)i*40 + u], acc);
    }
    red[isl][u] = acc;
    __syncthreads();
    if (tid < 64) {
        float s = red[0][tid] + red[1][tid] + red[2][tid] + red[3][tid];
        float x = (tid < 40) ? (s + bsm[tid]) : -1e30f;
        float mx = x;
        #pragma unroll
        for (int off = 32; off >= 1; off >>= 1) mx = fmaxf(mx, __shfl_xor(mx, off));
        float e = (tid < 40) ? expf(x - mx) : 0.f;
        float ssum = e;
        #pragma unroll
        for (int off = 32; off >= 1; off >>= 1) ssum += __shfl_xor(ssum, off);
        if (tid < 40) out[b*40 + tid] = e / ssum;
    }
}

extern "C" void kernel_launch(void* const* d_in, const int* in_sizes, int n_in,
                              void* d_out, int out_size, void* d_ws, size_t ws_size,
                              hipStream_t stream)
{
    const float* points = (const float*)d_in[0];
    const float* feats  = (const float*)d_in[1];
    const float* W0   = (const float*)d_in[2];
    const float* b0   = (const float*)d_in[3];
    const float* W1   = (const float*)d_in[4];
    const float* W2   = (const float*)d_in[5];
    const float* W3   = (const float*)d_in[6];
    const float* Wfc1 = (const float*)d_in[7];
    const float* bfc1 = (const float*)d_in[8];
    const float* Wfc2 = (const float*)d_in[9];
    const float* bfc2 = (const float*)d_in[10];
    const float* Wsm  = (const float*)d_in[11];
    const float* bsm  = (const float*)d_in[12];
    float* out = (float*)d_out;

    char* ws = (char*)d_ws;
    unsigned int* hmax = (unsigned int*)ws;              // 32 KB (poison OK, biased keys)
    float* t1 = (float*)(ws + 32*1024);                  // 64 KB
    float* t2 = (float*)(ws + 96*1024);                  // 32 KB
    float* dummy = (float*)(ws + 120*1024);              // warmup sink
    uint4* Wb = (uint4*)(ws + 128*1024);                 // 96 KB (single-bf16 W)

    wsplit_kernel<<<24, 256, 0, stream>>>(W0, W1, W2, W3, Wb);
    main_kernel<<<NBLK, 512, 0, stream>>>(points, feats, b0, Wb, hmax,
                                          Wfc1, Wfc2, dummy);
    fc1_kernel<<<256, 256, 0, stream>>>(hmax, Wfc1, bfc1, t1);
    fc2_kernel<<<128, 256, 0, stream>>>(t1, Wfc2, bfc2, t2);
    fc3_kernel<<<32, 256, 0, stream>>>(t2, Wsm, bsm, out);
}

// Round 12
// 154.060 us; speedup vs baseline: 1.2420x; 1.0060x over previous
//
#include <hip/hip_runtime.h>
#include <hip/hip_bf16.h>
#include <math.h>

#define B_ 32
#define N_ 2048
#define C_ 64
#define M_ 512
#define KNN_ 32
#define RADIUS_ 0.4f
#define RCUT2 0.16016f        // conservative candidate cut (exact mask re-applied later)
#define GSCALE_ 6.2383246250f
#define TT 4                  // targets per block (amortizes Wb L2 stream)
#define NWAVE 8               // 512 threads; ~28KB LDS -> 4 blocks/CU = 32 waves/CU
#define SEGCAP 40             // per-(wave,target) candidate segment cap
#define NBLK 4096

typedef __attribute__((ext_vector_type(8))) short bf16x8;
typedef __attribute__((ext_vector_type(4))) float f32x4;
union FragU { uint4 q; bf16x8 h; unsigned int u[4]; };

// ---- main kernel LDS layout (dword offsets), TT=4, 512 threads ----
// per-target region t*1616 (t<4), phase-overlaid:
//   phase A (P1/P3a):  Y[k][16] stride 17 at [0,544); FS hi [k2][64] s=66
//                      at [560,1616)   (bf16-RNE f only)
//   phase B (P3b/P4):  zh plane [p][j] bf16, row stride 200 hw, hw [0,3200)
//                      (z bf16-RNE only)
// cand u64 [8w][4t][SEGCAP]: dwords [3232, 5792) -- overlays regions 2,3;
//   dead after select (barrier), before any Y/FS write there.
// WGT transposed [t][s][k] f32: [6464, 6848), per-t stride 96
// Precision budget: W bf16 (r7), f bf16 (r8), z bf16 (r10) — three 2^-9
// sources, measured 1 output ULP.  A=Y.w MUST stay hi/lo: r11 dropped it
// and error exploded 120x (nonlinear amplification through norms+FC+softmax).
#define ZT_ 1616
#define ZTH (ZT_*2)            // 3232 halfwords per target region
#define RSTH 200               // z row stride (halfwords); 400B = 16B-aligned
#define FSH 560
#define CAND_OFF 3232
#define WGT_OFF  6464
#define WGT_TS   96
#define SM_TOTAL 6848          // 27392 B (+~1.3KB arrays) -> 4 blocks/CU (wave cap)

// v_cvt_pk_bf16_f32: D.lo16 = bf16_rne(a), D.hi16 = bf16_rne(b) — one VALU op.
__device__ inline unsigned cvt_pk_bf16(float a, float b) {
    unsigned r;
    asm("v_cvt_pk_bf16_f32 %0, %1, %2" : "=v"(r) : "v"(a), "v"(b));
    return r;
}

// Pair split via cvt_pk: hw = hi(a0)|hi(a1)<<16, lw = lo(a0)|lo(a1)<<16.
// hi = RNE-bf16(a), lo = RNE-bf16(a - hi): residual bound 2^-18|a|.
__device__ inline void split_pair(float a0, float a1, unsigned& hw, unsigned& lw) {
    hw = cvt_pk_bf16(a0, a1);
    float r0 = a0 - __uint_as_float(hw << 16);
    float r1 = a1 - __uint_as_float(hw & 0xffff0000u);
    lw = cvt_pk_bf16(r0, r1);
}

// =====================================================================
// Setup kernel: W0..W3 -> single-bf16 (RNE) B-fragments for mfma 16x16x32.
// frag id = (l*6+ks)*4+nt.
// =====================================================================
__global__ __launch_bounds__(256) void wsplit_kernel(
    const float* __restrict__ W0, const float* __restrict__ W1,
    const float* __restrict__ W2, const float* __restrict__ W3,
    uint4* __restrict__ Wb)
{
    int gid = blockIdx.x * 256 + threadIdx.x;      // 96 frags * 64 lanes = 6144
    int lane = gid & 63, frag = gid >> 6;
    int nt = frag & 3;
    int ls = frag >> 2, ks = ls % 6, l = ls / 6;
    const float* W = (l==0) ? W0 : (l==1) ? W1 : (l==2) ? W2 : W3;
    int n = nt*16 + (lane & 15), quad = lane >> 4;
    unsigned int d[4];
    #pragma unroll
    for (int dd = 0; dd < 4; ++dd) {
        unsigned int two[2];
        #pragma unroll
        for (int e = 0; e < 2; ++e) {
            int k = ks*32 + quad*8 + dd*2 + e;
            __hip_bfloat16 hb = __float2bfloat16(W[k*64 + n]);   // RNE
            two[e] = *(unsigned short*)&hb;
        }
        d[dd] = two[0] | (two[1] << 16);
    }
    Wb[(size_t)frag*64 + lane] = make_uint4(d[0], d[1], d[2], d[3]);
}

// =====================================================================
// Main kernel (TT=4, 512 thr, 4 blocks/CU = 32 waves/CU): fused KNN
// (register scan) + SH/weights + MFMA z-einsum (wave = (t, n-half),
// A hi/lo bf16, f bf16, barrier-split read/write phases, single-plane
// bf16 z) + MFMA slab matmul (wave = (band, n-half), perm-free A-frags,
// pipelined disjoint Wb streams) + in-register band norms + atomicMax.
// XCD-aware block swizzle: each batch's 128 blocks co-locate on one XCD
// (assumes XCD = blockIdx % 8 round-robin; bijective, perf-only).
// =====================================================================
__global__ __launch_bounds__(512, 8) void main_kernel(
    const float* __restrict__ points, const float* __restrict__ feats,
    const float* __restrict__ b0, const uint4* __restrict__ Wb,
    unsigned int* __restrict__ hmax,
    const float* __restrict__ Wfc1, const float* __restrict__ Wfc2,
    float* __restrict__ dummy)
{
    __shared__ __align__(16) float smem[SM_TOTAL];
    __shared__ int sh_nbr[TT][32];
    __shared__ int sh_cnt[TT];
    __shared__ int cntk[NWAVE*TT];
    unsigned int* smemU = (unsigned int*)smem;
    unsigned short* smemH = (unsigned short*)smem;
    const int tid = threadIdx.x;
    // XCD swizzle: bid -> (xcd = bid&7, idx = bid>>3); batch = xcd*4 + idx>>7
    const int xcd = blockIdx.x & 7, idx = blockIdx.x >> 3;
    const int b = xcd*4 + (idx >> 7);
    const int mbase = (idx & 127) * TT;
    const float* pb = points + (size_t)b * N_ * 3;
    const int wv = tid >> 6, lane = tid & 63;

    // L3 warmup for the downstream FC chain (consumed at the end).
    float wm1 = Wfc1[(size_t)blockIdx.x*32 + (tid & 31)];   // 4096*32 = |Wfc1|
    float wm2 = Wfc2[(size_t)blockIdx.x*32 + (tid & 31)];   // 4096*32 = |Wfc2|

    // b0 preload for this wave's two n-tiles (band==0 only uses it)
    const int nh_pre = wv >> 2;
    float b0r[2];
    #pragma unroll
    for (int ntl = 0; ntl < 2; ++ntl)
        b0r[ntl] = b0[(nh_pre*2 + ntl)*16 + (lane & 15)];

    // ---- KNN scan: register-resident. Wave scans its eighth (256 points,
    //      4 per lane) against all TT targets. ----
    {
        unsigned long long* cand = (unsigned long long*)&smem[CAND_OFF];
        float tx[TT], ty[TT], tz[TT];
        #pragma unroll
        for (int c = 0; c < TT; ++c) {
            int m4 = 4*(mbase + c);
            tx[c] = pb[3*m4]; ty[c] = pb[3*m4+1]; tz[c] = pb[3*m4+2];
        }
        float px[4], py[4], pz[4];
        const float* ps = pb + 3*(wv*256 + lane);
        #pragma unroll
        for (int it = 0; it < 4; ++it) {
            px[it] = ps[it*192+0]; py[it] = ps[it*192+1]; pz[it] = ps[it*192+2];
        }
        int bcnt[TT];
        #pragma unroll
        for (int c = 0; c < TT; ++c) bcnt[c] = 0;
        #pragma unroll
        for (int it = 0; it < 4; ++it) {
            int i = wv*256 + it*64 + lane;
            #pragma unroll
            for (int c = 0; c < TT; ++c) {
                float dx = px[it] - tx[c], dy = py[it] - ty[c], dz = pz[it] - tz[c];
                float d2 = fmaf(dx,dx, fmaf(dy,dy, dz*dz));
                bool isc = d2 <= RCUT2;
                unsigned long long mk = __ballot(isc);
                if (isc) {
                    int pos = bcnt[c] + __popcll(mk & ((1ull<<lane)-1ull));
                    if (pos < SEGCAP)
                        cand[(size_t)(wv*TT+c)*SEGCAP + pos] =
                            ((unsigned long long)__float_as_uint(d2) << 32) | (unsigned)i;
                }
                bcnt[c] += __popcll(mk);
            }
        }
        if (lane == 0) {
            #pragma unroll
            for (int c = 0; c < TT; ++c)
                cntk[wv*TT+c] = bcnt[c] < SEGCAP ? bcnt[c] : SEGCAP;
        }
    }
    __syncthreads();   // cand + cntk visible

    // ---- select: wave t (t<4) merges 8 segments, picks 32-smallest SET ----
    if (wv < TT) {
        unsigned long long* cand = (unsigned long long*)&smem[CAND_OFF];
        const int t = wv;
        int os[NWAVE+1];
        os[0] = 0;
        #pragma unroll
        for (int w = 0; w < NWAVE; ++w) os[w+1] = os[w] + cntk[w*TT+t];
        int C = os[NWAVE] < 128 ? os[NWAVE] : 128;
        auto fetch = [&](int pos) -> unsigned long long {
            if (pos >= C) return ~0ull;
            int ws = 0, base = 0;
            #pragma unroll
            for (int w = 1; w < NWAVE; ++w)
                if (pos >= os[w]) { ws = w; base = os[w]; }
            return cand[(size_t)(ws*TT+t)*SEGCAP + (pos - base)];
        };
        unsigned long long kv0 = fetch(lane), kv1 = fetch(64 + lane);
        const unsigned long long lmask = (1ull << lane) - 1ull;
        if (C <= KNN_) {
            if (lane < KNN_) sh_nbr[t][lane] = (lane < C) ? (int)(kv0 & 0xffffffffu) : 0;
            if (lane == 0) sh_cnt[t] = C;
        } else {
            // Radix-select: largest thr with #{d2 < thr} < 32, on the d2
            // bit pattern (d2 in [0,0.25) => bits < 2^30, 30-step descent).
            unsigned d0 = (unsigned)(kv0 >> 32);   // invalid lanes = 0xFFFFFFFF
            unsigned d1 = (unsigned)(kv1 >> 32);
            unsigned thr = 0u;
            for (int bit = 29; bit >= 0; --bit) {
                unsigned mid = thr | (1u << bit);
                int cnt = __popcll(__ballot(d0 < mid)) + __popcll(__ballot(d1 < mid));
                if (cnt < KNN_) thr = mid;
            }
            // strictly-less set (size <= 31) + first E equals by lane order
            bool le0 = d0 < thr, le1 = d1 < thr;
            int cntL = __popcll(__ballot(le0)) + __popcll(__ballot(le1));
            int E = KNN_ - cntL;                   // >= 1; #equals >= E
            unsigned long long me0 = __ballot(d0 == thr);
            unsigned long long me1 = __ballot(d1 == thr);
            int e0 = __popcll(me0);
            bool sel0 = le0 || ((d0 == thr) && (__popcll(me0 & lmask) < E));
            bool sel1 = le1 || ((d1 == thr) && (e0 + __popcll(me1 & lmask) < E));
            unsigned long long ms0 = __ballot(sel0);
            if (sel0) sh_nbr[t][__popcll(ms0 & lmask)] = (int)(kv0 & 0xffffffffu);
            int base0 = __popcll(ms0);
            unsigned long long ms1 = __ballot(sel1);
            if (sel1) sh_nbr[t][base0 + __popcll(ms1 & lmask)] = (int)(kv1 & 0xffffffffu);
            if (lane == 0) sh_cnt[t] = KNN_;
        }
    }
    __syncthreads();   // sh_nbr visible; cand dead (regions 2,3 writable)

    // ---- P1: wave = (t = wv&3, kh = wv>>2). Feats gather pre-issued into
    //      registers; geometry on waves 0..3 lanes 0..31; FS staging 8 pairs
    //      (bf16-RNE hi only).
    {
        const int t = wv & 3, kh = wv >> 2;
        const float* fb = feats + (size_t)b * N_ * C_;
        float fv0[8], fv1[8];
        #pragma unroll
        for (int j = 0; j < 8; ++j) {
            int k2 = kh*8 + j;
            fv0[j] = fb[(size_t)sh_nbr[t][2*k2]   * C_ + lane];
            fv1[j] = fb[(size_t)sh_nbr[t][2*k2+1] * C_ + lane];
        }
        if (wv < TT && lane < 32) {
            int k = lane;
            int n = sh_nbr[t][k];
            int m4 = 4*(mbase + t);
            float x = pb[3*n]   - pb[3*m4];
            float y = pb[3*n+1] - pb[3*m4+1];
            float z = pb[3*n+2] - pb[3*m4+2];
            float d2 = x*x + y*y + z*z;
            float dist = sqrtf(fmaxf(d2, 1e-12f));
            float inv = 1.0f / dist;
            float dx = x*inv, dy = y*inv, dz = z*inv;
            float x2 = dx*dx, y2 = dy*dy, z2 = dz*dz;
            float yv[16];
            yv[0]  = 0.282095f;
            yv[1]  = 0.488603f*dy;  yv[2] = 0.488603f*dz;  yv[3] = 0.488603f*dx;
            yv[4]  = 1.092548f*dx*dy;
            yv[5]  = 1.092548f*dy*dz;
            yv[6]  = 0.315392f*(3.0f*z2-1.0f);
            yv[7]  = 1.092548f*dx*dz;
            yv[8]  = 0.546274f*(x2-y2);
            yv[9]  = 0.590044f*dy*(3.0f*x2-y2);
            yv[10] = 2.890611f*dx*dy*dz;
            yv[11] = 0.457046f*dy*(5.0f*z2-1.0f);
            yv[12] = 0.373176f*dz*(5.0f*z2-3.0f);
            yv[13] = 0.457046f*dx*(5.0f*z2-1.0f);
            yv[14] = 1.445306f*dz*(x2-y2);
            yv[15] = 0.590044f*dx*(x2-3.0f*y2);
            float* Yp = &smem[t*ZT_ + k*17];
            #pragma unroll
            for (int p = 0; p < 16; ++p) Yp[p] = yv[p];
            float dn = dist * (1.0f/RADIUS_);
            bool ok = (k < sh_cnt[t]) && (dn <= 1.0f);
            float w0 = 0.f, w1 = 0.f, w2 = 0.f;
            if (ok) {
                float dd0 = dn, dd1 = dn - 0.5f, dd2 = dn - 1.0f;
                w0 = __expf(-GSCALE_*dd0*dd0);
                w1 = __expf(-GSCALE_*dd1*dd1);
                w2 = __expf(-GSCALE_*dd2*dd2);
            }
            float s0 = w0, s1 = w1, s2 = w2;
            #pragma unroll
            for (int off = 16; off >= 1; off >>= 1) {
                s0 += __shfl_xor(s0, off);
                s1 += __shfl_xor(s1, off);
                s2 += __shfl_xor(s2, off);
            }
            w0 /= (s0 + 1e-8f);
            w1 /= (s1 + 1e-8f);
            w2 /= (s2 + 1e-8f);
            // transposed WGT[t][s][k]: conflict-free broadcast reads in P3
            smem[WGT_OFF + t*WGT_TS +      k] = w0;
            smem[WGT_OFF + t*WGT_TS + 32 + k] = w1;
            smem[WGT_OFF + t*WGT_TS + 64 + k] = w2;
        }
        // stage FS hi (loads issued above; latency hidden under geometry VALU)
        #pragma unroll
        for (int j = 0; j < 8; ++j) {
            int k2 = kh*8 + j;
            smemU[t*ZT_ + FSH + k2*66 + lane] = cvt_pk_bf16(fv0[j], fv1[j]);
        }
    }
    __syncthreads();   // Y, WGT, FS all visible

    // ---- P3a: z-einsum via MFMA. wave = (t, nh): 2 n-tiles each.
    //      A = (Y.w_s) in hi/lo bf16 (2^-18 acc — REQUIRED, see budget),
    //      B = bf16 f.  12 MFMA/wave. ----
    f32x4 zacc[3][2];
    {
        const int t = wv & 3, nh = wv >> 2;
        const int quad = lane >> 4, col = lane & 15;
        float yv8[8];
        #pragma unroll
        for (int d = 0; d < 8; ++d)
            yv8[d] = smem[t*ZT_ + (quad*8 + d)*17 + col];
        FragU ah[3], al[3];
        #pragma unroll
        for (int s = 0; s < 3; ++s) {
            #pragma unroll
            for (int i = 0; i < 4; ++i) {
                float we = smem[WGT_OFF + t*WGT_TS + s*32 + quad*8 + 2*i];
                float wo = smem[WGT_OFF + t*WGT_TS + s*32 + quad*8 + 2*i + 1];
                split_pair(yv8[2*i]*we, yv8[2*i+1]*wo, ah[s].u[i], al[s].u[i]);
            }
        }
        #pragma unroll
        for (int s = 0; s < 3; ++s)
            #pragma unroll
            for (int nl = 0; nl < 2; ++nl) zacc[s][nl] = (f32x4){0.f,0.f,0.f,0.f};
        #pragma unroll
        for (int nl = 0; nl < 2; ++nl) {
            int n = (nh*2 + nl)*16 + col;
            FragU bh;
            #pragma unroll
            for (int i = 0; i < 4; ++i) {
                int k2 = quad*4 + i;
                bh.u[i] = smemU[t*ZT_ + FSH + k2*66 + n];
            }
            #pragma unroll
            for (int s = 0; s < 3; ++s) {
                zacc[s][nl] = __builtin_amdgcn_mfma_f32_16x16x32_bf16(ah[s].h, bh.h, zacc[s][nl], 0, 0, 0);
                zacc[s][nl] = __builtin_amdgcn_mfma_f32_16x16x32_bf16(al[s].h, bh.h, zacc[s][nl], 0, 0, 0);
            }
        }
    }
    __syncthreads();   // ALL waves' Y/FS reads drained before z plane overwrites

    // ---- P3b: write zh plane as bf16-RNE halfwords (disjoint j per wave) ----
    {
        const int t = wv & 3, nh = wv >> 2;
        const int quad = lane >> 4, col = lane & 15;
        #pragma unroll
        for (int s = 0; s < 3; ++s) {
            #pragma unroll
            for (int nl = 0; nl < 2; ++nl) {
                #pragma unroll
                for (int r = 0; r < 4; ++r) {
                    int p = quad*4 + r;
                    int j = s*64 + (nh*2+nl)*16 + col;
                    float a = zacc[s][nl][r];
                    smemH[t*ZTH + p*RSTH + j] =
                        (unsigned short)cvt_pk_bf16(a, a);
                }
            }
        }
    }

    // ---- P4: slab matmul; wave = (band, nh). Perm-free A-frags straight
    //      from the zh plane; single-bf16 W, software-pipelined Wb loads
    //      (ks=0 issued before the z barrier). In-register band norms.
    {
        const int bp0[4] = {0,1,4,9};
        const int bsz[4] = {1,3,5,7};
        const int band = wv & 3, nh = wv >> 2;
        FragU bcur[2], bnxt[2];
        #pragma unroll
        for (int ntl = 0; ntl < 2; ++ntl)
            bcur[ntl].q = Wb[(size_t)((band*6 + 0)*4 + nh*2 + ntl)*64 + lane];
        __syncthreads();   // z plane fully visible (Wb loads already in flight)

        const int sz = bsz[band], p0 = bp0[band];
        const int rows = 2*sz;
        const int quad = lane >> 4, col = lane & 15;
        int gc = col < rows-1 ? col : rows-1;
        int tl = gc >= sz ? 1 : 0;
        int pA = p0 + gc - tl*sz;
        const unsigned hbA = tl*ZTH + pA*RSTH;     // halfword base, target {0,1}
        const unsigned hbB = hbA + 2*ZTH;          // target {2,3}, same p
        f32x4 acc[2][2];                           // [ti][ntl]
        #pragma unroll
        for (int ti = 0; ti < 2; ++ti)
            #pragma unroll
            for (int ntl = 0; ntl < 2; ++ntl) acc[ti][ntl] = (f32x4){0.f,0.f,0.f,0.f};

        #pragma unroll
        for (int ks = 0; ks < 6; ++ks) {
            if (ks < 5) {
                #pragma unroll
                for (int ntl = 0; ntl < 2; ++ntl)
                    bnxt[ntl].q = Wb[(size_t)((band*6 + ks+1)*4 + nh*2 + ntl)*64 + lane];
            }
            FragU ahA, ahB;
            ahA.q = *(const uint4*)&smemH[hbA + ks*32 + quad*8];
            ahB.q = *(const uint4*)&smemH[hbB + ks*32 + quad*8];
            #pragma unroll
            for (int ntl = 0; ntl < 2; ++ntl) {
                acc[0][ntl] = __builtin_amdgcn_mfma_f32_16x16x32_bf16(ahA.h, bcur[ntl].h, acc[0][ntl], 0, 0, 0);
                acc[1][ntl] = __builtin_amdgcn_mfma_f32_16x16x32_bf16(ahB.h, bcur[ntl].h, acc[1][ntl], 0, 0, 0);
            }
            #pragma unroll
            for (int ntl = 0; ntl < 2; ++ntl) bcur[ntl] = bnxt[ntl];
        }
        // In-register band norms for 4 targets; quad-reduce via shfl_xor(16/32).
        float sq[2][4];                            // [ntl][tg = ti*2 + tl2]
        #pragma unroll
        for (int ntl = 0; ntl < 2; ++ntl)
            #pragma unroll
            for (int tg = 0; tg < 4; ++tg) sq[ntl][tg] = 0.f;
        #pragma unroll
        for (int r = 0; r < 4; ++r) {
            int row = quad*4 + r;
            bool valid = row < rows;
            int tl2 = row >= sz ? 1 : 0;
            #pragma unroll
            for (int ti = 0; ti < 2; ++ti) {
                #pragma unroll
                for (int ntl = 0; ntl < 2; ++ntl) {
                    float o = acc[ti][ntl][r];
                    if (band == 0) o += b0r[ntl];
                    if (valid) sq[ntl][ti*2 + tl2] += o*o;
                }
            }
        }
        #pragma unroll
        for (int ntl = 0; ntl < 2; ++ntl) {
            #pragma unroll
            for (int tg = 0; tg < 4; ++tg) {
                float v = sq[ntl][tg];
                v += __shfl_xor(v, 16);
                v += __shfl_xor(v, 32);
                sq[ntl][tg] = v;
            }
        }
        if (quad == 0) {
            #pragma unroll
            for (int ntl = 0; ntl < 2; ++ntl) {
                float m = fmaxf(fmaxf(sq[ntl][0], sq[ntl][1]),
                                fmaxf(sq[ntl][2], sq[ntl][3]));
                float h = sqrtf(fmaxf(m, 1e-8f));
                // biased key: order-preserving, beats the 0xAA poison -> no memset.
                atomicMax(&hmax[b*256 + band*64 + (nh*2 + ntl)*16 + col],
                          __float_as_uint(h) ^ 0x80000000u);
            }
        }
    }

    // consume the warmup loads (branch practically never taken)
    if (__float_as_uint(wm1 + wm2) == 0xdeadbeefu) dummy[0] = wm1;
}

// =====================================================================
// FC head, round-8 split (evidence: 5-dispatch split beat merged fc23).
// =====================================================================
__global__ __launch_bounds__(256) void fc1_kernel(
    const unsigned int* __restrict__ hmaxk,
    const float* __restrict__ Wfc1, const float* __restrict__ bfc1,
    float* __restrict__ t1)
{
    __shared__ float h[256];
    __shared__ float red[4][80];
    const int b = blockIdx.x >> 3, uc = blockIdx.x & 7;
    const int tid = threadIdx.x;
    const int u = tid & 63, iq = tid >> 6;
    h[tid] = __uint_as_float(hmaxk[b*256 + tid] ^ 0x80000000u);
    __syncthreads();
    float acc = 0.f;
    const float* Wp = Wfc1 + uc*64 + u;
    #pragma unroll 8
    for (int i = iq*64; i < iq*64 + 64; ++i)
        acc = fmaf(h[i], Wp[(size_t)i*512], acc);
    red[iq][u] = acc;
    __syncthreads();
    if (iq == 0) {
        float s = red[0][u] + red[1][u] + red[2][u] + red[3][u] + bfc1[uc*64 + u];
        t1[b*512 + uc*64 + u] = fmaxf(s, 0.f);
    }
}

__global__ __launch_bounds__(256) void fc2_kernel(
    const float* __restrict__ t1,
    const float* __restrict__ Wfc2, const float* __restrict__ bfc2,
    float* __restrict__ t2)
{
    __shared__ float t1s[512];
    __shared__ float red[4][80];
    const int b = blockIdx.x >> 2, uc = blockIdx.x & 3;
    const int tid = threadIdx.x;
    const int u = tid & 63, isl = tid >> 6;
    t1s[tid]       = t1[b*512 + tid];
    t1s[256 + tid] = t1[b*512 + 256 + tid];
    __syncthreads();
    float acc = 0.f;
    const float* Wp = Wfc2 + uc*64 + u;
    #pragma unroll 8
    for (int i = isl*128; i < isl*128 + 128; ++i)
        acc = fmaf(t1s[i], Wp[(size_t)i*256], acc);
    red[isl][u] = acc;
    __syncthreads();
    if (isl == 0) {
        float s = red[0][u] + red[1][u] + red[2][u] + red[3][u] + bfc2[uc*64 + u];
        t2[b*256 + uc*64 + u] = fmaxf(s, 0.f);
    }
}

__global__ __launch_bounds__(256) void fc3_kernel(
    const float* __restrict__ t2,
    const float* __restrict__ Wsm, const float* __restrict__ bsm,
    float* __restrict__ out)
{
    __shared__ float t2s[256];
    __shared__ float red[4][80];
    const int b = blockIdx.x;
    const int tid = threadIdx.x;
    const int u = tid & 63, isl = tid >> 6;
    t2s[tid] = t2[b*256 + tid];
    __syncthreads();
    float acc = 0.f;
    if (u < 40) {
        #pragma unroll 8
        for (int i = isl*64; i < isl*64 + 64; ++i)
            acc = fmaf(t2s[i], Wsm[(size_t)i*40 + u], acc);
    }
    red[isl][u] = acc;
    __syncthreads();
    if (tid < 64) {
        float s = red[0][tid] + red[1][tid] + red[2][tid] + red[3][tid];
        float x = (tid < 40) ? (s + bsm[tid]) : -1e30f;
        float mx = x;
        #pragma unroll
        for (int off = 32; off >= 1; off >>= 1) mx = fmaxf(mx, __shfl_xor(mx, off));
        float e = (tid < 40) ? expf(x - mx) : 0.f;
        float ssum = e;
        #pragma unroll
        for (int off = 32; off >= 1; off >>= 1) ssum += __shfl_xor(ssum, off);
        if (tid < 40) out[b*40 + tid] = e / ssum;
    }
}

extern "C" void kernel_launch(void* const* d_in, const int* in_sizes, int n_in,
                              void* d_out, int out_size, void* d_ws, size_t ws_size,
                              hipStream_t stream)
{
    const float* points = (const float*)d_in[0];
    const float* feats  = (const float*)d_in[1];
    const float* W0   = (const float*)d_in[2];
    const float* b0   = (const float*)d_in[3];
    const float* W1   = (const float*)d_in[4];
    const float* W2   = (const float*)d_in[5];
    const float* W3   = (const float*)d_in[6];
    const float* Wfc1 = (const float*)d_in[7];
    const float* bfc1 = (const float*)d_in[8];
    const float* Wfc2 = (const float*)d_in[9];
    const float* bfc2 = (const float*)d_in[10];
    const float* Wsm  = (const float*)d_in[11];
    const float* bsm  = (const float*)d_in[12];
    float* out = (float*)d_out;

    char* ws = (char*)d_ws;
    unsigned int* hmax = (unsigned int*)ws;              // 32 KB (poison OK, biased keys)
    float* t1 = (float*)(ws + 32*1024);                  // 64 KB
    float* t2 = (float*)(ws + 96*1024);                  // 32 KB
    float* dummy = (float*)(ws + 120*1024);              // warmup sink
    uint4* Wb = (uint4*)(ws + 128*1024);                 // 96 KB (single-bf16 W)

    wsplit_kernel<<<24, 256, 0, stream>>>(W0, W1, W2, W3, Wb);
    main_kernel<<<NBLK, 512, 0, stream>>>(points, feats, b0, Wb, hmax,
                                          Wfc1, Wfc2, dummy);
    fc1_kernel<<<256, 256, 0, stream>>>(hmax, Wfc1, bfc1, t1);
    fc2_kernel<<<128, 256, 0, stream>>>(t1, Wfc2, bfc2, t2);
    fc3_kernel<<<32, 256, 0, stream>>>(t2, Wsm, bsm, out);
}